// Round 7
// baseline (1640.921 us; speedup 1.0000x reference)
//
#include <hip/hip_runtime.h>
#include <math.h>

typedef short bf16x8 __attribute__((ext_vector_type(8)));
typedef float f32x4 __attribute__((ext_vector_type(4)));
typedef unsigned short u16;
typedef unsigned int u32;

// float-region offsets in ws
#define WSUMS 0
#define TOTWS 1
#define WSUM_OFF 2
#define TOTW_OFF 8194
#define SCL_F 16386
#define WB_BYTE 98432      // start of bf16/u16 region (byte offset)

// u16-region offsets
#define GWI_U 0            // [384][32]   gru Wih (cols 0..29, pad 0)
#define GWH_U 12288        // [384][128]  gru Whh
#define EO_U  61440        // [7][512][256]  enc (Wih|Whh)
#define DO_U  978944       // [512][320]  dec packed
#define XG_U  1142784      // [7][8192][24][16] gru x feats
#define XD_U  23162880     // [8192][24][16]    dec x feats

__constant__ int cLAG[8] = {144,120,96,72,48,24,0,168};

__device__ __forceinline__ float sig_(float x){ return 1.0f/(1.0f+__expf(-x)); }
__device__ __forceinline__ float th_(float x){ float e=__expf(2.0f*x); return 1.0f - 2.0f/(e+1.0f); }
__device__ __forceinline__ u16 f2b(float x){ u32 u=__float_as_uint(x); return (u16)((u + 0x7fffu + ((u>>16)&1u))>>16); }
__device__ __forceinline__ float b2f(u16 v){ return __uint_as_float(((u32)v)<<16); }
__device__ __forceinline__ void pin(bf16x8 &x){
  f32x4 t = __builtin_bit_cast(f32x4, x);
  asm volatile("" : "+v"(t));
  x = __builtin_bit_cast(bf16x8, t);
}

#define MFMA(a,b,c) __builtin_amdgcn_mfma_f32_16x16x32_bf16(a,b,c,0,0,0)

__global__ void scale_kernel(const float* __restrict__ tgt,
                             const float* __restrict__ obs,
                             float* __restrict__ ws)
{
  __shared__ float s1[256], s2[256];
  int b = blockIdx.x*256 + threadIdx.x;
  float wsum=0.f, totw=0.f;
  const float* tr = tgt + b*336 + 168;
  const float* wr = obs + b*336 + 168;
  for(int t=0;t<168;t++){ float w=wr[t]; wsum += fabsf(tr[t])*w; totw += w; }
  ws[WSUM_OFF + b] = wsum;
  ws[TOTW_OFF + b] = totw;
  s1[threadIdx.x]=wsum; s2[threadIdx.x]=totw;
  __syncthreads();
  for(int s=128;s>0;s>>=1){
    if(threadIdx.x<s){ s1[threadIdx.x]+=s1[threadIdx.x+s]; s2[threadIdx.x]+=s2[threadIdx.x+s]; }
    __syncthreads();
  }
  if(threadIdx.x==0){ atomicAdd(&ws[WSUMS], s1[0]); atomicAdd(&ws[TOTWS], s2[0]); }
}

__global__ void prep_w(const float* __restrict__ gWih, const float* __restrict__ gWhh,
                       const float* __restrict__ eWih, const float* __restrict__ eWhh,
                       const float* __restrict__ dWih, const float* __restrict__ dWhh,
                       float* __restrict__ ws)
{
  u16* WU = (u16*)((char*)ws + WB_BYTE);
  int tid = blockIdx.x*blockDim.x + threadIdx.x;
  int nt = gridDim.x*blockDim.x;
  for(int i=tid;i<12288;i+=nt){ int n=i>>5,k=i&31; WU[GWI_U+i]=(k<30)?f2b(gWih[n*30+k]):(u16)0; }
  for(int i=tid;i<49152;i+=nt){ int n=i>>7,k=i&127; WU[GWH_U+i]=f2b(gWhh[n*128+k]); }
  for(int i=tid;i<917504;i+=nt){
    int s=i>>17,r2=i&131071,n=r2>>8,k=r2&255;
    float v=(k<128)?eWih[(s*512+n)*128+k]:eWhh[(s*512+n)*128+(k-128)];
    WU[EO_U+i]=f2b(v);
  }
  for(int i=tid;i<163840;i+=nt){
    int n=i/320, k=i-n*320; float v;
    if(k<128)       v=dWih[n*180+30+k];
    else if(k<136)  v=dWih[n*180+(k-128)];
    else if(k<140)  v=dWih[n*180+8+(k-136)];
    else if(k<144)  v=dWih[n*180+158+(k-140)];
    else if(k<162)  v=dWih[n*180+12+(k-144)];
    else if(k<180)  v=dWih[n*180+162+(k-162)];
    else if(k<192)  v=0.f;
    else            v=dWhh[n*128+(k-192)];
    WU[DO_U+i]=f2b(v);
  }
}

__global__ void prep_x(const float* __restrict__ tgt, const float* __restrict__ ptf,
                       const float* __restrict__ ftf, float* __restrict__ ws)
{
  __shared__ float inv_l[64];
  u16* WU = (u16*)((char*)ws + WB_BYTE);
  const int tid = threadIdx.x;
  const int b0 = blockIdx.x*64;
  if(tid<64){
    int b=b0+tid;
    float wsumv=ws[WSUM_OFF+b], totw=ws[TOTW_OFF+b];
    float def=ws[WSUMS]/fmaxf(ws[TOTWS],1.f);
    float sc=fmaxf(1e-10f,(wsumv>0.f)?wsumv/fmaxf(totw,1.f):def);
    ws[SCL_F+b]=sc; inv_l[tid]=1.f/sc;
  }
  __syncthreads();
  for(int idx=tid; idx<64*168; idx+=256){
    int bl=idx/168, gt=idx-bl*168; int b=b0+bl;
    float iv=inv_l[bl];
    __align__(16) u16 row[16];
    #pragma unroll
    for(int j=0;j<8;j++) row[j]=f2b(tgt[b*336+cLAG[j]+gt]*iv);
    const float* pp=ptf+((size_t)(b*336+168+gt))*4;
    #pragma unroll
    for(int j=0;j<4;j++) row[8+j]=f2b(pp[j]);
    row[12]=row[13]=row[14]=row[15]=0;
    int seg=gt/24, t=gt-seg*24;
    u16* dst=WU+XG_U+(((size_t)seg*8192+b)*24+t)*16;
    *(uint4*)dst=*(const uint4*)row; *(uint4*)(dst+8)=*(const uint4*)(row+8);
  }
  for(int idx=tid; idx<64*24; idx+=256){
    int bl=idx/24, t=idx-bl*24; int b=b0+bl;
    float iv=inv_l[bl];
    __align__(16) u16 row[16];
    #pragma unroll
    for(int j=0;j<8;j++) row[j]=f2b(tgt[b*336+cLAG[j]+t]*iv);
    #pragma unroll
    for(int j=0;j<4;j++) row[8+j]=f2b(ptf[((size_t)(b*336+168+t))*4+j]);
    #pragma unroll
    for(int j=0;j<4;j++) row[12+j]=f2b(ftf[b*96+t*4+j]);
    u16* dst=WU+XD_U+((size_t)b*24+t)*16;
    *(uint4*)dst=*(const uint4*)row; *(uint4*)(dst+8)=*(const uint4*)(row+8);
  }
}

// 16 waves. Wave w<8 owns n-tiles {w, w+16} = gates (i,g) for hcols w*16+l15.
// Wave w>=8 owns {w, w+16} = gates (f,o) for hcols (w-8)*16+l15, plus the c-state.
// Cell split: w<8 computes p=sig(i)*tanh(g) -> pbuf; w>=8 does c'=sig(f)*c+p, h=sig(o)*tanh(c').
// beta(r,t) = (t>>2)*64 + r*4 + (t&3): encbuf row index (t-group-major).
__global__ __launch_bounds__(1024,4)
void deepar_main(const int* __restrict__ cat, const float* __restrict__ sreal,
                 const float* __restrict__ emb,
                 const float* __restrict__ gbih, const float* __restrict__ gbhh,
                 const float* __restrict__ encb, const float* __restrict__ decb,
                 const float* __restrict__ outW, const float* __restrict__ outb,
                 float* __restrict__ ws, float* __restrict__ out)
{
  const u16* __restrict__ WU=(const u16*)((const char*)ws+WB_BYTE);

  __shared__ __align__(16) u16 encbuf[384*136];   // enc_out / hv, in place (beta rows)
  __shared__ __align__(16) u16 Ast[2][16*136];    // enc/dec x-tile, double-buffered
  __shared__ __align__(16) u16 Xast[2][64*40];    // GRU x tile (statics prebuilt)
  __shared__ __align__(16) u16 Xdast[16*72];      // dec extra feats (statics prebuilt)
  __shared__ __align__(16) u16 hstash[2][16*136]; // recurrent h, double-buffered
  __shared__ float pbuf[128*17];                  // i*g partial exchange (pitch 17: conflict-free)
  __shared__ u16 statb[16][18];
  __shared__ float scl_s[16];
  __shared__ float outw_s[128];
  __shared__ float red[16][8];
  __shared__ float outb_s;

  const int tid=threadIdx.x;
  const int b0=blockIdx.x*16;
  const int wv=tid>>6, lane=tid&63, quad=lane>>4, l15=lane&15;

  if(tid<16) scl_s[tid]=ws[SCL_F+b0+tid];
  if(tid<128) outw_s[tid]=outW[tid];
  if(tid==128) outb_s=outb[0];
  if(tid>=768){ int q=tid-768; int r=q>>4,k=q&15; statb[r][k]=f2b(emb[cat[b0+r]*16+k]); }
  { const uint4 z4={0,0,0,0};
    for(int i=tid;i<6528;i+=1024) *(uint4*)(encbuf+i*8)=z4;        // 384*136 u16
    for(int i=tid;i<544;i+=1024)  *(uint4*)(&hstash[0][0]+i*8)=z4; // 2*16*136 u16
  }
  __syncthreads();
  if(tid<16){ statb[tid][16]=f2b(sreal[b0+tid]); statb[tid][17]=f2b(logf(scl_s[tid])); }
  __syncthreads();
  for(int i=tid;i<1280;i+=1024){ int a=i/20, k=i-a*20+12;
    u16 v=(k<30)?statb[a>>2][k-12]:(u16)0;
    Xast[0][a*40+k]=v; Xast[1][a*40+k]=v; }
  for(int i=tid;i<896;i+=1024){ int rr=i/56, k=i-rr*56+16;
    u16 v; if(k<34) v=statb[rr][k-16]; else if(k<52) v=statb[rr][k-34]; else v=0;
    Xdast[rr*72+k]=v; }
  __syncthreads();

  float cst[4]={0.f,0.f,0.f,0.f};       // c-state: meaningful on waves 8..15
  int p=0;                              // hstash parity
  const int wc = wv&7;                  // col-group for GRU / cell
  const int hcE = ((wv>=8)?(wv-8):wv)*16 + l15;  // enc/dec hidden col this wave's pair covers

  for(int seg=0;seg<7;seg++){
    // ---- GRU weights: 15 frags/wave (gate-sequenced), fits in regs ----
    const int mg = wv>>3;               // m-group: waves 0-7 -> mt {0,1}, 8-15 -> mt {2,3}
    bf16x8 gwi[3]; bf16x8 gwh[3][4];
    float gsum[2], gni, gnh;
    {
      #pragma unroll
      for(int j=0;j<3;j++){
        int nb=(wc+j*8)*16+l15;
        gwi[j]=*(const bf16x8*)(WU+GWI_U+nb*32+quad*8); pin(gwi[j]);
        #pragma unroll
        for(int kt=0;kt<4;kt++){ gwh[j][kt]=*(const bf16x8*)(WU+GWH_U+nb*128+kt*32+quad*8); pin(gwh[j][kt]); }
        if(j<2) gsum[j]=gbih[nb]+gbhh[nb];
        else { gni=gbih[nb]; gnh=gbhh[nb]; }
      }
    }

    // ================= GRU: 6 chunks x 64 A-rows; wave handles 2 m-tiles, 3 gates =================
    for(int c=0;c<6;c++){
      u16* Xb = &Xast[c&1][0];
      if(tid<128){ int a=tid>>1;
        const u16* src=WU+XG_U+(((size_t)seg*8192+b0+(a>>2))*24+4*c+(a&3))*16;
        if(tid&1) *(uint2*)(Xb+a*40+8)=*(const uint2*)(src+8);
        else      *(uint4*)(Xb+a*40)  =*(const uint4*)src; }
      __syncthreads();

      const u16* ebase = encbuf + (size_t)(c*64)*136;
      f32x4 rg2[2], zg2[2], ni2[2], nh2[2];
      // gates r, z (bias folded: x+h in one acc)
      #pragma unroll
      for(int j=0;j<2;j++){
        f32x4 a2[2];
        #pragma unroll
        for(int m=0;m<2;m++){
          a2[m]=(f32x4){gsum[j],gsum[j],gsum[j],gsum[j]};
          bf16x8 af=*(const bf16x8*)(Xb+((mg*2+m)*16+l15)*40+quad*8);
          a2[m]=MFMA(af,gwi[j],a2[m]);
          #pragma unroll
          for(int kt=0;kt<4;kt++){
            bf16x8 ah=*(const bf16x8*)(ebase+((mg*2+m)*16+l15)*136+kt*32+quad*8);
            a2[m]=MFMA(ah,gwh[j][kt],a2[m]);
          }
        }
        #pragma unroll
        for(int m=0;m<2;m++)
          #pragma unroll
          for(int r=0;r<4;r++){ float s=sig_(a2[m][r]); if(j==0) rg2[m][r]=s; else zg2[m][r]=s; }
      }
      // gate n: x-part and h-part kept separate
      #pragma unroll
      for(int m=0;m<2;m++){
        ni2[m]=(f32x4){gni,gni,gni,gni};
        nh2[m]=(f32x4){gnh,gnh,gnh,gnh};
        bf16x8 af=*(const bf16x8*)(Xb+((mg*2+m)*16+l15)*40+quad*8);
        ni2[m]=MFMA(af,gwi[2],ni2[m]);
        #pragma unroll
        for(int kt=0;kt<4;kt++){
          bf16x8 ah=*(const bf16x8*)(ebase+((mg*2+m)*16+l15)*136+kt*32+quad*8);
          nh2[m]=MFMA(ah,gwh[2][kt],nh2[m]);
        }
      }
      const int hc = wc*16+l15;
      u16 hv16[2][4];
      #pragma unroll
      for(int m=0;m<2;m++)
        #pragma unroll
        for(int r=0;r<4;r++){
          int a=(mg*2+m)*16+quad*4+r;
          float hp=b2f(encbuf[(c*64+a)*136+hc]);
          float nn=th_(ni2[m][r] + rg2[m][r]*nh2[m][r]);
          hv16[m][r]=f2b((1.f-zg2[m][r])*nn + zg2[m][r]*hp);
        }
      __syncthreads();   // all reads of rows c done before in-place overwrite
      #pragma unroll
      for(int m=0;m<2;m++)
        #pragma unroll
        for(int r=0;r<4;r++)
          encbuf[(c*64+(mg*2+m)*16+quad*4+r)*136+hc]=hv16[m][r];
    }
    __syncthreads();     // hv complete

    // ================= encoder LSTM: 2 n-tiles/wave, full K, 16 frags =================
    bf16x8 we[2][8]; float be[2];
    {
      int ntA=wv, ntB=wv+16;
      be[0]=encb[seg*512+ntA*16+l15];
      be[1]=encb[seg*512+ntB*16+l15];
      const u16* base=WU+EO_U+(size_t)seg*131072;
      #pragma unroll
      for(int kt=0;kt<8;kt++){
        we[0][kt]=*(const bf16x8*)(base+(ntA*16+l15)*256+kt*32+quad*8); pin(we[0][kt]);
        we[1][kt]=*(const bf16x8*)(base+(ntB*16+l15)*256+kt*32+quad*8); pin(we[1][kt]);
      }
    }
    if(tid<256){ int row=tid>>4,q=tid&15;               // pre-stage Ast[0] (t=0)
      *(uint4*)(&Ast[0][row*136+q*8])=*(const uint4*)(encbuf+(row*4)*136+q*8); }
    for(int t=0;t<24;t++){
      __syncthreads();                                   // B1
      const u16* Ab=&Ast[t&1][0];
      const u16* Hb=&hstash[p][0];
      f32x4 acc0=(f32x4){be[0],be[0],be[0],be[0]};
      f32x4 acc1=(f32x4){be[1],be[1],be[1],be[1]};
      #pragma unroll
      for(int kt=0;kt<8;kt++){
        bf16x8 af=(kt<4)? *(const bf16x8*)(Ab+l15*136+kt*32+quad*8)
                        : *(const bf16x8*)(Hb+l15*136+(kt-4)*32+quad*8);
        acc0=MFMA(af,we[0][kt],acc0);
        acc1=MFMA(af,we[1][kt],acc1);
      }
      if(wv<8){  // gates i,g -> p
        #pragma unroll
        for(int r=0;r<4;r++)
          pbuf[hcE*17+quad*4+r]=sig_(acc0[r])*th_(acc1[r]);
      }
      __syncthreads();                                   // B2
      int pn=p^1;
      if(wv>=8){ // gates f,o + c-state + h-write
        int tb=(t>>2)*64+(t&3);
        #pragma unroll
        for(int r=0;r<4;r++){
          float fg=sig_(acc0[r]), og=sig_(acc1[r]);
          float c_=fg*cst[r]+pbuf[hcE*17+quad*4+r];
          cst[r]=c_;
          u16 hb=f2b(og*th_(c_));
          int row=quad*4+r;
          hstash[pn][row*136+hcE]=hb;
          encbuf[(tb+row*4)*136+hcE]=hb;
        }
      } else if(t<23 && tid<256){                        // stage Ast(t+1), disjoint rows
        int row=tid>>4,q=tid&15; int tb2=((t+1)>>2)*64+((t+1)&3);
        *(uint4*)(&Ast[(t+1)&1][row*136+q*8])=*(const uint4*)(encbuf+(tb2+row*4)*136+q*8);
      }
      p=pn;
    }
    __syncthreads();
  }

  // ================= decoder LSTM + projection =================
  bf16x8 wd[2][10]; float bd[2];
  {
    int ntA=wv, ntB=wv+16;
    bd[0]=decb[ntA*16+l15];
    bd[1]=decb[ntB*16+l15];
    #pragma unroll
    for(int kt=0;kt<10;kt++){
      wd[0][kt]=*(const bf16x8*)(WU+DO_U+(ntA*16+l15)*320+kt*32+quad*8); pin(wd[0][kt]);
      wd[1][kt]=*(const bf16x8*)(WU+DO_U+(ntB*16+l15)*320+kt*32+quad*8); pin(wd[1][kt]);
    }
  }
  for(int t=0;t<24;t++){
    int tb=(t>>2)*64+(t&3);
    u16* Ab=&Ast[t&1][0];
    if(tid<256){ int row=tid>>4,q=tid&15;
      *(uint4*)(Ab+row*136+q*8)=*(const uint4*)(encbuf+(tb+row*4)*136+q*8); }
    else if(tid<288){ int q=tid-256; int rr=q>>1;
      const u16* src=WU+XD_U+((size_t)(b0+rr)*24+t)*16;
      if(q&1) *(uint4*)(Xdast+rr*72+8)=*(const uint4*)(src+8);
      else    *(uint4*)(Xdast+rr*72)  =*(const uint4*)src; }
    __syncthreads();                                     // B1
    const u16* Hb=&hstash[p][0];
    f32x4 acc0=(f32x4){bd[0],bd[0],bd[0],bd[0]};
    f32x4 acc1=(f32x4){bd[1],bd[1],bd[1],bd[1]};
    #pragma unroll
    for(int kt=0;kt<10;kt++){
      bf16x8 af=(kt<4)? *(const bf16x8*)(Ab+l15*136+kt*32+quad*8)
              :(kt<6)? *(const bf16x8*)(Xdast+l15*72+(kt-4)*32+quad*8)
                     : *(const bf16x8*)(Hb+l15*136+(kt-6)*32+quad*8);
      acc0=MFMA(af,wd[0][kt],acc0);
      acc1=MFMA(af,wd[1][kt],acc1);
    }
    if(wv<8){
      #pragma unroll
      for(int r=0;r<4;r++)
        pbuf[hcE*17+quad*4+r]=sig_(acc0[r])*th_(acc1[r]);
    }
    __syncthreads();                                     // B2
    int pn=p^1;
    if(wv>=8){
      #pragma unroll
      for(int r=0;r<4;r++){
        float fg=sig_(acc0[r]), og=sig_(acc1[r]);
        float c_=fg*cst[r]+pbuf[hcE*17+quad*4+r];
        cst[r]=c_;
        hstash[pn][(quad*4+r)*136+hcE]=f2b(og*th_(c_));
      }
    }
    __syncthreads();                                     // B3: h complete
    if(tid<128){ int row=tid>>3,g=tid&7; float s=0.f;
      #pragma unroll
      for(int i=0;i<16;i++) s+=b2f(hstash[pn][row*136+g*16+i])*outw_s[g*16+i];
      red[row][g]=s; }
    __syncthreads();                                     // B4
    if(tid<16){ float s=outb_s;
      #pragma unroll
      for(int g=0;g<8;g++) s+=red[tid][g];
      out[(b0+tid)*24+t]=s*scl_s[tid]; }
    p=pn;
  }
}

extern "C" void kernel_launch(void* const* d_in, const int* in_sizes, int n_in,
                              void* d_out, int out_size, void* d_ws, size_t ws_size,
                              hipStream_t stream)
{
  (void)in_sizes; (void)n_in; (void)out_size; (void)ws_size;
  const int*   cat  = (const int*)d_in[0];
  const float* sreal= (const float*)d_in[1];
  const float* ptf  = (const float*)d_in[2];
  const float* tgt  = (const float*)d_in[3];
  const float* obs  = (const float*)d_in[4];
  const float* ftf  = (const float*)d_in[5];
  const float* emb  = (const float*)d_in[6];
  const float* gWih = (const float*)d_in[7];
  const float* gWhh = (const float*)d_in[8];
  const float* gbih = (const float*)d_in[9];
  const float* gbhh = (const float*)d_in[10];
  const float* eWih = (const float*)d_in[11];
  const float* eWhh = (const float*)d_in[12];
  const float* encb = (const float*)d_in[13];
  const float* dWih = (const float*)d_in[14];
  const float* dWhh = (const float*)d_in[15];
  const float* decb = (const float*)d_in[16];
  const float* outW = (const float*)d_in[17];
  const float* outb = (const float*)d_in[18];
  float* ws  = (float*)d_ws;
  float* out = (float*)d_out;

  hipMemsetAsync(d_ws, 0, 2*sizeof(float), stream);
  scale_kernel<<<dim3(8192/256), dim3(256), 0, stream>>>(tgt, obs, ws);
  prep_w<<<dim3(512), dim3(256), 0, stream>>>(gWih,gWhh,eWih,eWhh,dWih,dWhh,ws);
  prep_x<<<dim3(128), dim3(256), 0, stream>>>(tgt, ptf, ftf, ws);
  deepar_main<<<dim3(512), dim3(1024), 0, stream>>>(cat,sreal,emb,gbih,gbhh,encb,decb,
                                                    outW,outb,ws,out);
}

// Round 8
// 1420.756 us; speedup vs baseline: 1.1550x; 1.1550x over previous
//
#include <hip/hip_runtime.h>
#include <math.h>

typedef short bf16x8 __attribute__((ext_vector_type(8)));
typedef float f32x4 __attribute__((ext_vector_type(4)));
typedef unsigned short u16;
typedef unsigned int u32;

// float-region offsets in ws
#define WSUMS 0
#define TOTWS 1
#define WSUM_OFF 2
#define TOTW_OFF 8194
#define SCL_F 16386
#define WB_BYTE 98432      // start of bf16/u16 region (byte offset)

// u16-region offsets
#define GWI_U 0            // [384][32]   gru Wih (cols 0..29, pad 0)
#define GWH_U 12288        // [384][128]  gru Whh
#define EO_U  61440        // [7][512][256]  enc (Wih|Whh)
#define DO_U  978944       // [512][320]  dec packed
#define XG_U  1142784      // [7][8192][24][16] gru x feats
#define XD_U  23162880     // [8192][24][16]    dec x feats

__constant__ int cLAG[8] = {144,120,96,72,48,24,0,168};

__device__ __forceinline__ float sig_(float x){ return 1.0f/(1.0f+__expf(-x)); }
__device__ __forceinline__ float th_(float x){ float e=__expf(2.0f*x); return 1.0f - 2.0f/(e+1.0f); }
__device__ __forceinline__ u16 f2b(float x){ u32 u=__float_as_uint(x); return (u16)((u + 0x7fffu + ((u>>16)&1u))>>16); }
__device__ __forceinline__ float b2f(u16 v){ return __uint_as_float(((u32)v)<<16); }
__device__ __forceinline__ void pin(bf16x8 &x){
  f32x4 t = __builtin_bit_cast(f32x4, x);
  asm volatile("" : "+v"(t));
  x = __builtin_bit_cast(bf16x8, t);
}

#define MFMA(a,b,c) __builtin_amdgcn_mfma_f32_16x16x32_bf16(a,b,c,0,0,0)

__global__ void scale_kernel(const float* __restrict__ tgt,
                             const float* __restrict__ obs,
                             float* __restrict__ ws)
{
  __shared__ float s1[256], s2[256];
  int b = blockIdx.x*256 + threadIdx.x;
  float wsum=0.f, totw=0.f;
  const float* tr = tgt + b*336 + 168;
  const float* wr = obs + b*336 + 168;
  for(int t=0;t<168;t++){ float w=wr[t]; wsum += fabsf(tr[t])*w; totw += w; }
  ws[WSUM_OFF + b] = wsum;
  ws[TOTW_OFF + b] = totw;
  s1[threadIdx.x]=wsum; s2[threadIdx.x]=totw;
  __syncthreads();
  for(int s=128;s>0;s>>=1){
    if(threadIdx.x<s){ s1[threadIdx.x]+=s1[threadIdx.x+s]; s2[threadIdx.x]+=s2[threadIdx.x+s]; }
    __syncthreads();
  }
  if(threadIdx.x==0){ atomicAdd(&ws[WSUMS], s1[0]); atomicAdd(&ws[TOTWS], s2[0]); }
}

__global__ void prep_w(const float* __restrict__ gWih, const float* __restrict__ gWhh,
                       const float* __restrict__ eWih, const float* __restrict__ eWhh,
                       const float* __restrict__ dWih, const float* __restrict__ dWhh,
                       float* __restrict__ ws)
{
  u16* WU = (u16*)((char*)ws + WB_BYTE);
  int tid = blockIdx.x*blockDim.x + threadIdx.x;
  int nt = gridDim.x*blockDim.x;
  for(int i=tid;i<12288;i+=nt){ int n=i>>5,k=i&31; WU[GWI_U+i]=(k<30)?f2b(gWih[n*30+k]):(u16)0; }
  for(int i=tid;i<49152;i+=nt){ int n=i>>7,k=i&127; WU[GWH_U+i]=f2b(gWhh[n*128+k]); }
  for(int i=tid;i<917504;i+=nt){
    int s=i>>17,r2=i&131071,n=r2>>8,k=r2&255;
    float v=(k<128)?eWih[(s*512+n)*128+k]:eWhh[(s*512+n)*128+(k-128)];
    WU[EO_U+i]=f2b(v);
  }
  for(int i=tid;i<163840;i+=nt){
    int n=i/320, k=i-n*320; float v;
    if(k<128)       v=dWih[n*180+30+k];
    else if(k<136)  v=dWih[n*180+(k-128)];
    else if(k<140)  v=dWih[n*180+8+(k-136)];
    else if(k<144)  v=dWih[n*180+158+(k-140)];
    else if(k<162)  v=dWih[n*180+12+(k-144)];
    else if(k<180)  v=dWih[n*180+162+(k-162)];
    else if(k<192)  v=0.f;
    else            v=dWhh[n*128+(k-192)];
    WU[DO_U+i]=f2b(v);
  }
}

__global__ void prep_x(const float* __restrict__ tgt, const float* __restrict__ ptf,
                       const float* __restrict__ ftf, float* __restrict__ ws)
{
  __shared__ float inv_l[64];
  u16* WU = (u16*)((char*)ws + WB_BYTE);
  const int tid = threadIdx.x;
  const int b0 = blockIdx.x*64;
  if(tid<64){
    int b=b0+tid;
    float wsumv=ws[WSUM_OFF+b], totw=ws[TOTW_OFF+b];
    float def=ws[WSUMS]/fmaxf(ws[TOTWS],1.f);
    float sc=fmaxf(1e-10f,(wsumv>0.f)?wsumv/fmaxf(totw,1.f):def);
    ws[SCL_F+b]=sc; inv_l[tid]=1.f/sc;
  }
  __syncthreads();
  for(int idx=tid; idx<64*168; idx+=256){
    int bl=idx/168, gt=idx-bl*168; int b=b0+bl;
    float iv=inv_l[bl];
    __align__(16) u16 row[16];
    #pragma unroll
    for(int j=0;j<8;j++) row[j]=f2b(tgt[b*336+cLAG[j]+gt]*iv);
    const float* pp=ptf+((size_t)(b*336+168+gt))*4;
    #pragma unroll
    for(int j=0;j<4;j++) row[8+j]=f2b(pp[j]);
    row[12]=row[13]=row[14]=row[15]=0;
    int seg=gt/24, t=gt-seg*24;
    u16* dst=WU+XG_U+(((size_t)seg*8192+b)*24+t)*16;
    *(uint4*)dst=*(const uint4*)row; *(uint4*)(dst+8)=*(const uint4*)(row+8);
  }
  for(int idx=tid; idx<64*24; idx+=256){
    int bl=idx/24, t=idx-bl*24; int b=b0+bl;
    float iv=inv_l[bl];
    __align__(16) u16 row[16];
    #pragma unroll
    for(int j=0;j<8;j++) row[j]=f2b(tgt[b*336+cLAG[j]+t]*iv);
    #pragma unroll
    for(int j=0;j<4;j++) row[8+j]=f2b(ptf[((size_t)(b*336+168+t))*4+j]);
    #pragma unroll
    for(int j=0;j<4;j++) row[12+j]=f2b(ftf[b*96+t*4+j]);
    u16* dst=WU+XD_U+((size_t)b*24+t)*16;
    *(uint4*)dst=*(const uint4*)row; *(uint4*)(dst+8)=*(const uint4*)(row+8);
  }
}

// beta(r,t) = (t>>2)*64 + r*4 + (t&3): encbuf row index (t-group-major)
// LDS (136 KB) caps residency at 1 block/CU = 2 waves/EU. The v252-v255 entry
// clobber statically forces a 256-VGPR allocation (the allocator otherwise
// targets 4 waves/EU -> 128 regs -> weight spills, measured r3/r5/r6/r7).
__global__ __launch_bounds__(512,2)
__attribute__((amdgpu_waves_per_eu(2,2)))
void deepar_main(const int* __restrict__ cat, const float* __restrict__ sreal,
                 const float* __restrict__ emb,
                 const float* __restrict__ gbih, const float* __restrict__ gbhh,
                 const float* __restrict__ encb, const float* __restrict__ decb,
                 const float* __restrict__ outW, const float* __restrict__ outb,
                 float* __restrict__ ws, float* __restrict__ out)
{
  asm volatile("" ::: "v252","v253","v254","v255");   // force 256-VGPR allocation

  const u16* __restrict__ WU=(const u16*)((const char*)ws+WB_BYTE);

  __shared__ __align__(16) u16 encbuf[384*136];   // enc_out / hv, in place (beta rows)
  __shared__ __align__(16) u16 Ast[2][16*136];    // enc/dec x-tile, double-buffered
  __shared__ __align__(16) u16 Xast[2][64*40];    // GRU x tile (statics prebuilt)
  __shared__ __align__(16) u16 Xdast[16*72];      // dec extra feats (statics prebuilt)
  __shared__ __align__(16) u16 hstash[2][16*136]; // recurrent h, double-buffered
  __shared__ u16 statb[16][18];
  __shared__ float scl_s[16];
  __shared__ float outw_s[128];
  __shared__ float red[16][8];
  __shared__ float outb_s;

  const int tid=threadIdx.x;
  const int b0=blockIdx.x*16;
  const int wv=tid>>6, lane=tid&63, quad=lane>>4, l15=lane&15;

  if(tid<16) scl_s[tid]=ws[SCL_F+b0+tid];
  if(tid<128) outw_s[tid]=outW[tid];
  if(tid==128) outb_s=outb[0];
  if(tid>=256){ int q=tid-256; int r=q>>4,k=q&15; statb[r][k]=f2b(emb[cat[b0+r]*16+k]); }
  { const uint4 z4={0,0,0,0};
    for(int i=tid;i<6528;i+=512) *(uint4*)(encbuf+i*8)=z4;        // 6528*8 = 384*136
    for(int i=tid;i<544;i+=512)  *(uint4*)(&hstash[0][0]+i*8)=z4; // 544*8 = 2*16*136
  }
  __syncthreads();
  if(tid<16){ statb[tid][16]=f2b(sreal[b0+tid]); statb[tid][17]=f2b(logf(scl_s[tid])); }
  __syncthreads();
  // prebuild t-invariant columns of GRU / dec A-tiles
  for(int i=tid;i<1280;i+=512){ int a=i/20, k=i-a*20+12;
    u16 v=(k<30)?statb[a>>2][k-12]:(u16)0;
    Xast[0][a*40+k]=v; Xast[1][a*40+k]=v; }
  for(int i=tid;i<896;i+=512){ int rr=i/56, k=i-rr*56+16;
    u16 v; if(k<34) v=statb[rr][k-16]; else if(k<52) v=statb[rr][k-34]; else v=0;
    Xdast[rr*72+k]=v; }
  __syncthreads();

  float gbi[3], gbh[3];
  #pragma unroll
  for(int j=0;j<3;j++){ int nb=(wv+j*8)*16+l15; gbi[j]=gbih[nb]; gbh[j]=gbhh[nb]; }

  float cst[4]={0.f,0.f,0.f,0.f};
  const int hc=wv*16+l15;
  int p=0;                                  // hstash parity

  for(int seg=0;seg<7;seg++){
    // ---- GRU weights: load + pin (live this phase only) ----
    bf16x8 gwi[3]; bf16x8 gwh[3][4];
    #pragma unroll
    for(int j=0;j<3;j++){
      int nb=(wv+j*8)*16+l15;
      gwi[j]=*(const bf16x8*)(WU+GWI_U+nb*32+quad*8); pin(gwi[j]);
      #pragma unroll
      for(int kt=0;kt<4;kt++){ gwh[j][kt]=*(const bf16x8*)(WU+GWH_U+nb*128+kt*32+quad*8); pin(gwh[j][kt]); }
    }

    // ================= GRU: 6 chunks x 64 A-rows (16 r x 4 t), in place =================
    for(int c=0;c<6;c++){
      u16* Xb = &Xast[c&1][0];
      if(tid<128){ int a=tid>>1;
        const u16* src=WU+XG_U+(((size_t)seg*8192+b0+(a>>2))*24+4*c+(a&3))*16;
        if(tid&1) *(uint2*)(Xb+a*40+8)=*(const uint2*)(src+8);
        else      *(uint4*)(Xb+a*40)  =*(const uint4*)src; }
      __syncthreads();

      f32x4 ai[3][4], ah[3][4];
      #pragma unroll
      for(int j=0;j<3;j++)
        #pragma unroll
        for(int mt=0;mt<4;mt++){
          ai[j][mt]=(f32x4){gbi[j],gbi[j],gbi[j],gbi[j]};
          ah[j][mt]=(f32x4){gbh[j],gbh[j],gbh[j],gbh[j]};
        }
      #pragma unroll
      for(int mt=0;mt<4;mt++){
        bf16x8 af=*(const bf16x8*)(Xb+(mt*16+l15)*40+quad*8);
        #pragma unroll
        for(int j=0;j<3;j++) ai[j][mt]=MFMA(af,gwi[j],ai[j][mt]);
      }
      const u16* ebase=encbuf+(size_t)(c*64)*136;
      #pragma unroll
      for(int kt=0;kt<4;kt++)
        #pragma unroll
        for(int mt=0;mt<4;mt++){
          bf16x8 af=*(const bf16x8*)(ebase+(mt*16+l15)*136+kt*32+quad*8);
          #pragma unroll
          for(int j=0;j<3;j++) ah[j][mt]=MFMA(af,gwh[j][kt],ah[j][mt]);
        }
      u16 hv16[4][4];
      #pragma unroll
      for(int mt=0;mt<4;mt++)
        #pragma unroll
        for(int reg=0;reg<4;reg++){
          int a=mt*16+quad*4+reg;
          float rg=sig_(ai[0][mt][reg]+ah[0][mt][reg]);
          float zg=sig_(ai[1][mt][reg]+ah[1][mt][reg]);
          float hp=b2f(encbuf[(c*64+a)*136+hc]);
          float nn=th_(ai[2][mt][reg]+rg*ah[2][mt][reg]);
          hv16[mt][reg]=f2b((1.f-zg)*nn+zg*hp);
        }
      __syncthreads();   // all reads of rows c done before in-place overwrite
      #pragma unroll
      for(int mt=0;mt<4;mt++)
        #pragma unroll
        for(int reg=0;reg<4;reg++)
          encbuf[(c*64+mt*16+quad*4+reg)*136+hc]=hv16[mt][reg];
    }

    // ================= encoder LSTM: resident weights, 24 steps =================
    bf16x8 we[4][8]; float be[4];
    #pragma unroll
    for(int j=0;j<4;j++){
      int nb=(wv+j*8)*16+l15;
      be[j]=encb[seg*512+nb];
      #pragma unroll
      for(int kt=0;kt<8;kt++){
        we[j][kt]=*(const bf16x8*)(WU+EO_U+(size_t)seg*131072+nb*256+kt*32+quad*8);
        pin(we[j][kt]);
      }
    }
    for(int t=0;t<24;t++){
      int tb=(t>>2)*64+(t&3);
      u16* Ab=&Ast[t&1][0];
      // stage(t): reads rows(t) written >=1 barrier ago; disjoint from writes(t) below
      if(tid<256){ int row=tid>>4,q=tid&15;
        *(uint4*)(Ab+row*136+q*8)=*(const uint4*)(encbuf+(tb+row*4)*136+q*8); }
      __syncthreads();
      const u16* Hb=&hstash[p][0];
      f32x4 acc[4];
      #pragma unroll
      for(int j=0;j<4;j++) acc[j]=(f32x4){be[j],be[j],be[j],be[j]};
      #pragma unroll
      for(int kt=0;kt<8;kt++){
        bf16x8 af=(kt<4)? *(const bf16x8*)(Ab+l15*136+kt*32+quad*8)
                        : *(const bf16x8*)(Hb+l15*136+(kt-4)*32+quad*8);
        #pragma unroll
        for(int j=0;j<4;j++) acc[j]=MFMA(af,we[j][kt],acc[j]);
      }
      u16 hnew[4];
      #pragma unroll
      for(int reg=0;reg<4;reg++){
        float ig=sig_(acc[0][reg]),fg=sig_(acc[1][reg]);
        float gg=th_(acc[2][reg]), og=sig_(acc[3][reg]);
        float c_=fg*cst[reg]+ig*gg; cst[reg]=c_;
        hnew[reg]=f2b(og*th_(c_));
      }
      int pn=p^1;
      u16* Hw=&hstash[pn][0];
      #pragma unroll
      for(int reg=0;reg<4;reg++){
        int row=quad*4+reg;
        Hw[row*136+hc]=hnew[reg];            // opposite buffer: no read hazard
        encbuf[(tb+row*4)*136+hc]=hnew[reg]; // rows(t): staged pre-barrier, safe
      }
      p=pn;
    }
  }

  // ================= decoder LSTM + projection =================
  bf16x8 wd[4][10]; float bd[4];
  #pragma unroll
  for(int j=0;j<4;j++){
    int nb=(wv+j*8)*16+l15;
    bd[j]=decb[nb];
    #pragma unroll
    for(int kt=0;kt<10;kt++){
      wd[j][kt]=*(const bf16x8*)(WU+DO_U+nb*320+kt*32+quad*8);
      pin(wd[j][kt]);
    }
  }
  for(int t=0;t<24;t++){
    int tb=(t>>2)*64+(t&3);
    u16* Ab=&Ast[t&1][0];
    if(tid<256){ int row=tid>>4,q=tid&15;
      *(uint4*)(Ab+row*136+q*8)=*(const uint4*)(encbuf+(tb+row*4)*136+q*8); }
    else if(tid<288){ int q=tid-256; int rr=q>>1;
      const u16* src=WU+XD_U+((size_t)(b0+rr)*24+t)*16;
      if(q&1) *(uint4*)(Xdast+rr*72+8)=*(const uint4*)(src+8);
      else    *(uint4*)(Xdast+rr*72)  =*(const uint4*)src; }
    __syncthreads();
    const u16* Hb=&hstash[p][0];
    f32x4 acc[4];
    #pragma unroll
    for(int j=0;j<4;j++) acc[j]=(f32x4){bd[j],bd[j],bd[j],bd[j]};
    #pragma unroll
    for(int kt=0;kt<10;kt++){
      bf16x8 af=(kt<4)? *(const bf16x8*)(Ab+l15*136+kt*32+quad*8)
              :(kt<6)? *(const bf16x8*)(Xdast+l15*72+(kt-4)*32+quad*8)
                     : *(const bf16x8*)(Hb+l15*136+(kt-6)*32+quad*8);
      #pragma unroll
      for(int j=0;j<4;j++) acc[j]=MFMA(af,wd[j][kt],acc[j]);
    }
    u16 hnew[4];
    #pragma unroll
    for(int reg=0;reg<4;reg++){
      float ig=sig_(acc[0][reg]),fg=sig_(acc[1][reg]);
      float gg=th_(acc[2][reg]), og=sig_(acc[3][reg]);
      float c_=fg*cst[reg]+ig*gg; cst[reg]=c_;
      hnew[reg]=f2b(og*th_(c_));
    }
    int pn=p^1;
    #pragma unroll
    for(int reg=0;reg<4;reg++)
      hstash[pn][(quad*4+reg)*136+hc]=hnew[reg];
    __syncthreads();      // projection needs the full new h row
    if(tid<128){ int row=tid>>3,g=tid&7; float s=0.f;
      #pragma unroll
      for(int i=0;i<16;i++) s+=b2f(hstash[pn][row*136+g*16+i])*outw_s[g*16+i];
      red[row][g]=s; }
    __syncthreads();
    if(tid<16){ float s=outb_s;
      #pragma unroll
      for(int g=0;g<8;g++) s+=red[tid][g];
      out[(b0+tid)*24+t]=s*scl_s[tid]; }
    p=pn;
  }
}

extern "C" void kernel_launch(void* const* d_in, const int* in_sizes, int n_in,
                              void* d_out, int out_size, void* d_ws, size_t ws_size,
                              hipStream_t stream)
{
  (void)in_sizes; (void)n_in; (void)out_size; (void)ws_size;
  const int*   cat  = (const int*)d_in[0];
  const float* sreal= (const float*)d_in[1];
  const float* ptf  = (const float*)d_in[2];
  const float* tgt  = (const float*)d_in[3];
  const float* obs  = (const float*)d_in[4];
  const float* ftf  = (const float*)d_in[5];
  const float* emb  = (const float*)d_in[6];
  const float* gWih = (const float*)d_in[7];
  const float* gWhh = (const float*)d_in[8];
  const float* gbih = (const float*)d_in[9];
  const float* gbhh = (const float*)d_in[10];
  const float* eWih = (const float*)d_in[11];
  const float* eWhh = (const float*)d_in[12];
  const float* encb = (const float*)d_in[13];
  const float* dWih = (const float*)d_in[14];
  const float* dWhh = (const float*)d_in[15];
  const float* decb = (const float*)d_in[16];
  const float* outW = (const float*)d_in[17];
  const float* outb = (const float*)d_in[18];
  float* ws  = (float*)d_ws;
  float* out = (float*)d_out;

  hipMemsetAsync(d_ws, 0, 2*sizeof(float), stream);
  scale_kernel<<<dim3(8192/256), dim3(256), 0, stream>>>(tgt, obs, ws);
  prep_w<<<dim3(512), dim3(256), 0, stream>>>(gWih,gWhh,eWih,eWhh,dWih,dWhh,ws);
  prep_x<<<dim3(128), dim3(256), 0, stream>>>(tgt, ptf, ftf, ws);
  deepar_main<<<dim3(512), dim3(512), 0, stream>>>(cat,sreal,emb,gbih,gbhh,encb,decb,
                                                   outW,outb,ws,out);
}